// Round 8
// baseline (602.923 us; speedup 1.0000x reference)
//
#include <hip/hip_runtime.h>
#include <hip/hip_bf16.h>
#include <math.h>

#define N_USERS 20000
#define N_ENT   80000
#define N_NODES 100000
#define D 64
#define N_REL 33
#define E_EDGES 1250000
#define ELLW 40
#define EPS_ATT 1e-9f
#define EPS_NORM 1e-12f
#define RELP 68
#define LW 8
#define NPB (LW*2)
#define BKT_NODES 128
#define BKT_CAP 4096
#define N_BKT ((N_NODES + BKT_NODES - 1) / BKT_NODES)   // 782

__device__ __forceinline__ int out_row(int n){
  return (n >= N_USERS) ? (n - N_USERS) : (n + N_ENT);
}
__device__ __forceinline__ unsigned short f2bf(float f){
  unsigned u = __float_as_uint(f);
  return (unsigned short)((u + 0x7FFFu + ((u >> 16) & 1u)) >> 16);  // RNE
}
__device__ __forceinline__ float bf2f(unsigned short b){
  return __uint_as_float(((unsigned)b) << 16);
}
__device__ __forceinline__ float4 bfq(uint2 u){  // 4 packed bf16 -> float4
  float4 r;
  r.x = __uint_as_float(u.x << 16);
  r.y = __uint_as_float(u.x & 0xFFFF0000u);
  r.z = __uint_as_float(u.y << 16);
  r.w = __uint_as_float(u.y & 0xFFFF0000u);
  return r;
}

__global__ void k_zero(unsigned* __restrict__ bcnt){
  int i = blockIdx.x*blockDim.x + threadIdx.x;
  if (i < N_BKT) bcnt[i] = 0u;
}

// ego0 bf16 conversion + W pack + bucket append (dense-ish writes per bucket).
// bpack entry: (src&127)<<23 | rel<<17 | dst   (30 bits)
__global__ void k_init_scatter(const float* __restrict__ user, const float* __restrict__ ent,
                               const float* __restrict__ W1, const float* __restrict__ W2,
                               const int* __restrict__ src, const int* __restrict__ dst,
                               const int* __restrict__ rel,
                               unsigned short* __restrict__ ego, unsigned* __restrict__ wpack,
                               unsigned* __restrict__ bcnt, unsigned* __restrict__ bpack){
  int stride = gridDim.x*blockDim.x;
  int tid0 = blockIdx.x*blockDim.x + threadIdx.x;
  // W pack: blocked [c][j][e] layout as bf16 pairs (4096 u32 per matrix)
  for (int i = tid0; i < D*D/2; i += stride){
    int e0 = i*2;
    int c = e0 >> 8, j = (e0 >> 2) & 63, e = e0 & 3;
    int s0 = (4*c+e)*64 + j, s1 = (4*c+e+1)*64 + j;
    wpack[i]         = (unsigned)f2bf(W1[s0]) | ((unsigned)f2bf(W1[s1]) << 16);
    wpack[D*D/2 + i] = (unsigned)f2bf(W2[s0]) | ((unsigned)f2bf(W2[s1]) << 16);
  }
  // ego conversion
  const int total4 = N_NODES * D / 4;
  for (int i = tid0; i < total4; i += stride){
    int idx = i*4, n = idx >> 6, d = idx & 63;
    float4 v = (n < N_USERS) ? *(const float4*)(user + (size_t)n*D + d)
                             : *(const float4*)(ent + (size_t)(n-N_USERS)*D + d);
    uint2 p;
    p.x = (unsigned)f2bf(v.x) | ((unsigned)f2bf(v.y) << 16);
    p.y = (unsigned)f2bf(v.z) | ((unsigned)f2bf(v.w) << 16);
    *(uint2*)(ego + idx) = p;
  }
  // bucket append
  const int e4 = E_EDGES / 4;
  for (int i = tid0; i < e4; i += stride){
    int4 s = ((const int4*)src)[i];
    int4 d = ((const int4*)dst)[i];
    int4 r = ((const int4*)rel)[i];
    unsigned p, b;
    b = (unsigned)s.x >> 7; p = atomicAdd(&bcnt[b], 1u);
    if (p < BKT_CAP) bpack[(size_t)b*BKT_CAP + p] = (((unsigned)s.x & 127u) << 23) | ((unsigned)r.x << 17) | (unsigned)d.x;
    b = (unsigned)s.y >> 7; p = atomicAdd(&bcnt[b], 1u);
    if (p < BKT_CAP) bpack[(size_t)b*BKT_CAP + p] = (((unsigned)s.y & 127u) << 23) | ((unsigned)r.y << 17) | (unsigned)d.y;
    b = (unsigned)s.z >> 7; p = atomicAdd(&bcnt[b], 1u);
    if (p < BKT_CAP) bpack[(size_t)b*BKT_CAP + p] = (((unsigned)s.z & 127u) << 23) | ((unsigned)r.z << 17) | (unsigned)d.z;
    b = (unsigned)s.w >> 7; p = atomicAdd(&bcnt[b], 1u);
    if (p < BKT_CAP) bpack[(size_t)b*BKT_CAP + p] = (((unsigned)s.w & 127u) << 23) | ((unsigned)r.w << 17) | (unsigned)d.w;
  }
}

// One block per bucket: build the 128-node ELL slab in LDS (zero-init), then
// stream it + per-node counts to global with dense uint4 stores.
__global__ __launch_bounds__(256) void k_bucket(const unsigned* __restrict__ bcnt,
                                                const unsigned* __restrict__ bpack,
                                                unsigned* __restrict__ spack,
                                                unsigned* __restrict__ cnt){
  __shared__ unsigned lell[BKT_NODES*ELLW];   // 5120 u32 = 20 KB
  __shared__ unsigned lcnt[BKT_NODES];
  int b = blockIdx.x, t = threadIdx.x;
  for (int i = t; i < BKT_NODES*ELLW; i += 256) lell[i] = 0u;
  if (t < BKT_NODES) lcnt[t] = 0u;
  __syncthreads();
  unsigned ne = bcnt[b]; ne = ne < BKT_CAP ? ne : BKT_CAP;
  for (unsigned i = t; i < ne; i += 256u){
    unsigned pk = bpack[(size_t)b*BKT_CAP + i];
    unsigned nl = pk >> 23;
    unsigned p = atomicAdd(&lcnt[nl], 1u);
    if (p < ELLW) lell[nl*ELLW + p] = pk & 0x7FFFFFu;   // rel<<17 | dst
  }
  __syncthreads();
  unsigned nodeBase = (unsigned)b * BKT_NODES;
  unsigned nNodes = N_NODES - nodeBase;
  nNodes = nNodes < BKT_NODES ? nNodes : BKT_NODES;
  unsigned tot4 = (nNodes * ELLW) >> 2;                  // ELLW multiple of 4
  uint4* dst4 = (uint4*)(spack + (size_t)nodeBase * ELLW);
  const uint4* src4 = (const uint4*)lell;
  for (unsigned i = t; i < tot4; i += 256u) dst4[i] = src4[i];
  for (unsigned i = t; i < nNodes; i += 256u) cnt[nodeBase + i] = lcnt[i];
}

// One wave per 2 nodes. Wave-uniform two-phase edge loop (A's segment, flush,
// then B's). ELL spack chunk preloaded to registers, distributed via
// ds_bpermute. bf16 storage, f32 math.
template<bool FINAL>
__global__ __launch_bounds__(512, 7) void k_layer(const unsigned* __restrict__ cnt,
    const unsigned* __restrict__ spack, const unsigned* __restrict__ wpack,
    const float* __restrict__ relE,
    const unsigned short* __restrict__ egoin, unsigned short* __restrict__ egoout,
    const unsigned short* __restrict__ ego0, float* __restrict__ out){
  __shared__ unsigned sW1b[D*D/2], sW2b[D*D/2];
  __shared__ float srel[N_REL*RELP];
  __shared__ float sx1[NPB][D], sx2[NPB][D];
  int tid = threadIdx.x;
  for (int i = tid; i < D*D/2; i += 512){
    sW1b[i] = wpack[i];
    sW2b[i] = wpack[D*D/2 + i];
  }
  for (int i = tid; i < N_REL*D; i += 512){
    int r = i >> 6, k = i & 63;
    srel[r*RELP + k] = relE[i];
  }
  __syncthreads();

  int wave = tid >> 6, lane = tid & 63;
  int g = lane >> 4, q4 = (lane & 15) * 4;
  int slotA = wave*2, slotB = slotA + 1;
  int nA = blockIdx.x*NPB + slotA, nB = nA + 1;

  unsigned lenA = cnt[nA]; lenA = lenA < ELLW ? lenA : ELLW;
  unsigned lenB = cnt[nB]; lenB = lenB < ELLW ? lenB : ELLW;
  unsigned slotsA = (lenA + 3u) & ~3u;
  unsigned slotsB = (lenB + 3u) & ~3u;
  unsigned total  = slotsA + slotsB;
  unsigned baseA = (unsigned)nA * ELLW, baseB = (unsigned)nB * ELLW;

  float4 hA = bfq(*(const uint2*)(egoin + (size_t)nA*D + q4));
  float4 hB = bfq(*(const uint2*)(egoin + (size_t)nB*D + q4));

  float dn = 0.f;
  float4 ac = make_float4(0.f,0.f,0.f,0.f);
  float4 aA = make_float4(0.f,0.f,0.f,0.f);
  float4 aB = make_float4(0.f,0.f,0.f,0.f);
  bool flA = false;

  auto flush = [&](float4& aOut){
    #pragma unroll
    for (int m = 16; m <= 32; m <<= 1){
      dn   += __shfl_xor(dn,   m, 64);
      ac.x += __shfl_xor(ac.x, m, 64); ac.y += __shfl_xor(ac.y, m, 64);
      ac.z += __shfl_xor(ac.z, m, 64); ac.w += __shfl_xor(ac.w, m, 64);
    }
    float inv = 1.f / (dn + EPS_ATT);
    aOut = make_float4(ac.x*inv, ac.y*inv, ac.z*inv, ac.w*inv);
    dn = 0.f; ac = make_float4(0.f,0.f,0.f,0.f);
  };

  for (unsigned cb = 0; cb < total; cb += 64u){
    unsigned s = cb + (unsigned)lane;
    bool pA = s < slotsA;
    int ia = (int)s;            ia = ia < (int)lenA - 1 ? ia : (int)lenA - 1;
    int ib = (int)(s - slotsA); ib = ib < (int)lenB - 1 ? ib : (int)lenB - 1;
    ia = ia > 0 ? ia : 0;
    ib = ib > 0 ? ib : 0;
    unsigned pidx = pA ? (baseA + (unsigned)ia) : (baseB + (unsigned)ib);
    unsigned pk_pre = spack[pidx];

    unsigned rem = total - cb;
    unsigned cmax = rem < 64u ? rem : 64u;       // multiple of 4
    unsigned aRem = slotsA > cb ? slotsA - cb : 0u;
    int nitA = (int)((aRem < cmax ? aRem : cmax) >> 2);
    int nitT = (int)(cmax >> 2);

    #pragma unroll 1
    for (int ph = 0; ph < 2; ++ph){
      int it0 = ph ? nitA : 0;
      int it1 = ph ? nitT : nitA;
      float4 h = ph ? hB : hA;
      unsigned len = ph ? lenB : lenA;
      unsigned sBase = ph ? slotsA : 0u;
      for (int it = it0; it < it1; ++it){
        int sl = (it << 2) + g;
        unsigned pk = (unsigned)__builtin_amdgcn_ds_bpermute(sl << 2, (int)pk_pre);
        unsigned eidx = cb + (unsigned)sl - sBase;
        uint2 u = *(const uint2*)(egoin + (size_t)(pk & 0x1FFFFu)*D + q4);
        float4 rv = *(const float4*)&srel[(pk >> 17)*RELP + q4];
        float4 t = bfq(u);
        float p = (h.x*t.x)*rv.x;
        p = fmaf(h.y*t.y, rv.y, p);
        p = fmaf(h.z*t.z, rv.z, p);
        p = fmaf(h.w*t.w, rv.w, p);
        #pragma unroll
        for (int m = 1; m <= 8; m <<= 1) p += __shfl_xor(p, m, 64);
        float l = fmaxf(p, 0.01f*p);
        float ex = (eidx < len) ? __expf(l) : 0.f;
        dn += ex;
        ac.x = fmaf(ex, t.x, ac.x); ac.y = fmaf(ex, t.y, ac.y);
        ac.z = fmaf(ex, t.z, ac.z); ac.w = fmaf(ex, t.w, ac.w);
      }
      if (ph == 0 && !flA && slotsA <= cb + cmax){ flush(aA); flA = true; }
    }
  }
  if (!flA) flush(aA);   // total==0 / lenA==0 case
  flush(aB);

  if (g == 0){
    *(float4*)&sx1[slotA][q4] = make_float4(hA.x+aA.x, hA.y+aA.y, hA.z+aA.z, hA.w+aA.w);
    *(float4*)&sx2[slotA][q4] = make_float4(hA.x*aA.x, hA.y*aA.y, hA.z*aA.z, hA.w*aA.w);
    *(float4*)&sx1[slotB][q4] = make_float4(hB.x+aB.x, hB.y+aB.y, hB.z+aB.z, hB.w+aB.w);
    *(float4*)&sx2[slotB][q4] = make_float4(hB.x*aB.x, hB.y*aB.y, hB.z*aB.z, hB.w*aB.w);
  }

  float nvA = 0.f, nvB = 0.f;
  #pragma unroll
  for (int c = 0; c < 16; ++c){
    float4 w1 = bfq(*(const uint2*)&sW1b[c*128 + lane*2]);
    float4 w2 = bfq(*(const uint2*)&sW2b[c*128 + lane*2]);
    float4 xa1 = *(const float4*)&sx1[slotA][c*4];
    float4 xa2 = *(const float4*)&sx2[slotA][c*4];
    float4 xb1 = *(const float4*)&sx1[slotB][c*4];
    float4 xb2 = *(const float4*)&sx2[slotB][c*4];
    nvA = fmaf(xa1.x, w1.x, nvA); nvA = fmaf(xa1.y, w1.y, nvA);
    nvA = fmaf(xa1.z, w1.z, nvA); nvA = fmaf(xa1.w, w1.w, nvA);
    nvA = fmaf(xa2.x, w2.x, nvA); nvA = fmaf(xa2.y, w2.y, nvA);
    nvA = fmaf(xa2.z, w2.z, nvA); nvA = fmaf(xa2.w, w2.w, nvA);
    nvB = fmaf(xb1.x, w1.x, nvB); nvB = fmaf(xb1.y, w1.y, nvB);
    nvB = fmaf(xb1.z, w1.z, nvB); nvB = fmaf(xb1.w, w1.w, nvB);
    nvB = fmaf(xb2.x, w2.x, nvB); nvB = fmaf(xb2.y, w2.y, nvB);
    nvB = fmaf(xb2.z, w2.z, nvB); nvB = fmaf(xb2.w, w2.w, nvB);
  }
  nvA = fmaxf(nvA, 0.01f*nvA);
  nvB = fmaxf(nvB, 0.01f*nvB);
  float s2A = nvA*nvA, s2B = nvB*nvB;
  #pragma unroll
  for (int m = 1; m <= 32; m <<= 1){
    s2A += __shfl_xor(s2A, m, 64);
    s2B += __shfl_xor(s2B, m, 64);
  }
  nvA = nvA / fmaxf(sqrtf(s2A), EPS_NORM);
  nvB = nvB / fmaxf(sqrtf(s2B), EPS_NORM);

  if (FINAL){
    float z0A = bf2f(ego0[(size_t)nA*D + lane]);
    float z1A = bf2f(egoin[(size_t)nA*D + lane]);
    float z0B = bf2f(ego0[(size_t)nB*D + lane]);
    float z1B = bf2f(egoin[(size_t)nB*D + lane]);
    out[(size_t)out_row(nA)*D + lane] = (z0A + z1A + nvA) * (1.f/3.f);
    out[(size_t)out_row(nB)*D + lane] = (z0B + z1B + nvB) * (1.f/3.f);
  } else {
    egoout[(size_t)nA*D + lane] = f2bf(nvA);
    egoout[(size_t)nB*D + lane] = f2bf(nvB);
  }
}

extern "C" void kernel_launch(void* const* d_in, const int* in_sizes, int n_in,
                              void* d_out, int out_size, void* d_ws, size_t ws_size,
                              hipStream_t stream) {
  const float* user = (const float*)d_in[0];
  const float* ent  = (const float*)d_in[1];
  const float* relE = (const float*)d_in[2];
  const float* W1   = (const float*)d_in[3];
  const float* W2   = (const float*)d_in[4];
  const int*   src  = (const int*)d_in[5];
  const int*   dst  = (const int*)d_in[6];
  const int*   rel  = (const int*)d_in[7];
  float* out = (float*)d_out;

  char* ws = (char*)d_ws;
  unsigned short* ego0 = (unsigned short*)ws; ws += (size_t)N_NODES*D*sizeof(unsigned short);
  unsigned short* ego1 = (unsigned short*)ws; ws += (size_t)N_NODES*D*sizeof(unsigned short);
  unsigned* spack = (unsigned*)ws;            ws += (size_t)N_NODES*ELLW*sizeof(unsigned);
  unsigned* cnt = (unsigned*)ws;              ws += (size_t)N_NODES*sizeof(unsigned);
  unsigned* wpack = (unsigned*)ws;            ws += (size_t)D*D*sizeof(unsigned);
  unsigned* bcnt = (unsigned*)ws;             ws += (size_t)N_BKT*sizeof(unsigned);
  unsigned* bpack = (unsigned*)ws;            ws += (size_t)N_BKT*BKT_CAP*sizeof(unsigned);

  k_zero<<<(N_BKT+255)/256, 256, 0, stream>>>(bcnt);
  k_init_scatter<<<2048, 256, 0, stream>>>(user, ent, W1, W2, src, dst, rel,
                                           ego0, wpack, bcnt, bpack);
  k_bucket<<<N_BKT, 256, 0, stream>>>(bcnt, bpack, spack, cnt);

  const int lb = N_NODES / NPB;   // 6250
  k_layer<false><<<lb, 512, 0, stream>>>(cnt, spack, wpack, relE, ego0, ego1, ego0, out);
  k_layer<true ><<<lb, 512, 0, stream>>>(cnt, spack, wpack, relE, ego1, ego1, ego0, out);
}

// Round 9
// 355.539 us; speedup vs baseline: 1.6958x; 1.6958x over previous
//
#include <hip/hip_runtime.h>
#include <hip/hip_bf16.h>
#include <math.h>

#define N_USERS 20000
#define N_ENT   80000
#define N_NODES 100000
#define D 64
#define N_REL 33
#define E_EDGES 1250000
#define ELLW 40
#define EPS_ATT 1e-9f
#define EPS_NORM 1e-12f
#define RELP 68
#define LW 8
#define NPB (LW*2)
#define N_XCD 8
#define NODES_PER_XCD (N_NODES / N_XCD)   // 12500

__device__ __forceinline__ int out_row(int n){
  return (n >= N_USERS) ? (n - N_USERS) : (n + N_ENT);
}
__device__ __forceinline__ unsigned short f2bf(float f){
  unsigned u = __float_as_uint(f);
  return (unsigned short)((u + 0x7FFFu + ((u >> 16) & 1u)) >> 16);  // RNE
}
__device__ __forceinline__ float bf2f(unsigned short b){
  return __uint_as_float(((unsigned)b) << 16);
}
__device__ __forceinline__ float4 bfq(uint2 u){  // 4 packed bf16 -> float4
  float4 r;
  r.x = __uint_as_float(u.x << 16);
  r.y = __uint_as_float(u.x & 0xFFFF0000u);
  r.z = __uint_as_float(u.y << 16);
  r.w = __uint_as_float(u.y & 0xFFFF0000u);
  return r;
}

__global__ void k_zero(unsigned* __restrict__ cnt){
  int i = blockIdx.x*blockDim.x + threadIdx.x;
  if (i < N_NODES) cnt[i] = 0u;
}

// ego0 bf16 conversion + W pack + XCD-partitioned direct-ELL scatter.
// Block set (blockIdx&7)==k handles only src in [k*12500, (k+1)*12500): all
// spack/cnt lines for a node are written by ONE XCD -> dense single writeback.
// spack[n*ELLW + p] = rel<<17 | dst
__global__ void k_init_scatter(const float* __restrict__ user, const float* __restrict__ ent,
                               const float* __restrict__ W1, const float* __restrict__ W2,
                               const int* __restrict__ src, const int* __restrict__ dst,
                               const int* __restrict__ rel,
                               unsigned short* __restrict__ ego, unsigned* __restrict__ wpack,
                               unsigned* __restrict__ cnt, unsigned* __restrict__ spack){
  int stride = gridDim.x*blockDim.x;
  int tid0 = blockIdx.x*blockDim.x + threadIdx.x;
  // W pack: blocked [c][j][e] layout as bf16 pairs (4096 u32 per matrix)
  for (int i = tid0; i < D*D/2; i += stride){
    int e0 = i*2;
    int c = e0 >> 8, j = (e0 >> 2) & 63, e = e0 & 3;
    int s0 = (4*c+e)*64 + j, s1 = (4*c+e+1)*64 + j;
    wpack[i]         = (unsigned)f2bf(W1[s0]) | ((unsigned)f2bf(W1[s1]) << 16);
    wpack[D*D/2 + i] = (unsigned)f2bf(W2[s0]) | ((unsigned)f2bf(W2[s1]) << 16);
  }
  // ego conversion
  const int total4 = N_NODES * D / 4;
  for (int i = tid0; i < total4; i += stride){
    int idx = i*4, n = idx >> 6, d = idx & 63;
    float4 v = (n < N_USERS) ? *(const float4*)(user + (size_t)n*D + d)
                             : *(const float4*)(ent + (size_t)(n-N_USERS)*D + d);
    uint2 p;
    p.x = (unsigned)f2bf(v.x) | ((unsigned)f2bf(v.y) << 16);
    p.y = (unsigned)f2bf(v.z) | ((unsigned)f2bf(v.w) << 16);
    *(uint2*)(ego + idx) = p;
  }
  // XCD-partitioned ELL scatter: 8 block-sets each scan all edges, keep 1/8
  int xcd = blockIdx.x & (N_XCD-1);
  int rank = blockIdx.x >> 3;                        // 0..255
  int nlo = xcd * NODES_PER_XCD, nhi = nlo + NODES_PER_XCD;
  const int e4 = E_EDGES / 4;
  int et = rank*256 + threadIdx.x;                   // 0..65535
  int estride = (gridDim.x >> 3) * 256;              // 65536
  for (int i = et; i < e4; i += estride){
    int4 s = ((const int4*)src)[i];
    int4 d = ((const int4*)dst)[i];
    int4 r = ((const int4*)rel)[i];
    unsigned p;
    if (s.x >= nlo && s.x < nhi){
      p = atomicAdd(&cnt[s.x], 1u);
      if (p < ELLW) spack[(size_t)s.x*ELLW + p] = ((unsigned)r.x << 17) | (unsigned)d.x;
    }
    if (s.y >= nlo && s.y < nhi){
      p = atomicAdd(&cnt[s.y], 1u);
      if (p < ELLW) spack[(size_t)s.y*ELLW + p] = ((unsigned)r.y << 17) | (unsigned)d.y;
    }
    if (s.z >= nlo && s.z < nhi){
      p = atomicAdd(&cnt[s.z], 1u);
      if (p < ELLW) spack[(size_t)s.z*ELLW + p] = ((unsigned)r.z << 17) | (unsigned)d.z;
    }
    if (s.w >= nlo && s.w < nhi){
      p = atomicAdd(&cnt[s.w], 1u);
      if (p < ELLW) spack[(size_t)s.w*ELLW + p] = ((unsigned)r.w << 17) | (unsigned)d.w;
    }
  }
}

// One wave per 2 nodes. Wave-uniform two-phase edge loop (A's segment, flush,
// then B's). ELL spack chunk preloaded to registers, distributed via
// ds_bpermute. bf16 storage, f32 math.
template<bool FINAL>
__global__ __launch_bounds__(512, 7) void k_layer(const unsigned* __restrict__ cnt,
    const unsigned* __restrict__ spack, const unsigned* __restrict__ wpack,
    const float* __restrict__ relE,
    const unsigned short* __restrict__ egoin, unsigned short* __restrict__ egoout,
    const unsigned short* __restrict__ ego0, float* __restrict__ out){
  __shared__ unsigned sW1b[D*D/2], sW2b[D*D/2];
  __shared__ float srel[N_REL*RELP];
  __shared__ float sx1[NPB][D], sx2[NPB][D];
  int tid = threadIdx.x;
  for (int i = tid; i < D*D/2; i += 512){
    sW1b[i] = wpack[i];
    sW2b[i] = wpack[D*D/2 + i];
  }
  for (int i = tid; i < N_REL*D; i += 512){
    int r = i >> 6, k = i & 63;
    srel[r*RELP + k] = relE[i];
  }
  __syncthreads();

  int wave = tid >> 6, lane = tid & 63;
  int g = lane >> 4, q4 = (lane & 15) * 4;
  int slotA = wave*2, slotB = slotA + 1;
  int nA = blockIdx.x*NPB + slotA, nB = nA + 1;

  unsigned lenA = cnt[nA]; lenA = lenA < ELLW ? lenA : ELLW;
  unsigned lenB = cnt[nB]; lenB = lenB < ELLW ? lenB : ELLW;
  unsigned slotsA = (lenA + 3u) & ~3u;
  unsigned slotsB = (lenB + 3u) & ~3u;
  unsigned total  = slotsA + slotsB;
  unsigned baseA = (unsigned)nA * ELLW, baseB = (unsigned)nB * ELLW;

  float4 hA = bfq(*(const uint2*)(egoin + (size_t)nA*D + q4));
  float4 hB = bfq(*(const uint2*)(egoin + (size_t)nB*D + q4));

  float dn = 0.f;
  float4 ac = make_float4(0.f,0.f,0.f,0.f);
  float4 aA = make_float4(0.f,0.f,0.f,0.f);
  float4 aB = make_float4(0.f,0.f,0.f,0.f);
  bool flA = false;

  auto flush = [&](float4& aOut){
    #pragma unroll
    for (int m = 16; m <= 32; m <<= 1){
      dn   += __shfl_xor(dn,   m, 64);
      ac.x += __shfl_xor(ac.x, m, 64); ac.y += __shfl_xor(ac.y, m, 64);
      ac.z += __shfl_xor(ac.z, m, 64); ac.w += __shfl_xor(ac.w, m, 64);
    }
    float inv = 1.f / (dn + EPS_ATT);
    aOut = make_float4(ac.x*inv, ac.y*inv, ac.z*inv, ac.w*inv);
    dn = 0.f; ac = make_float4(0.f,0.f,0.f,0.f);
  };

  for (unsigned cb = 0; cb < total; cb += 64u){
    unsigned s = cb + (unsigned)lane;
    bool pA = s < slotsA;
    int ia = (int)s;            ia = ia < (int)lenA - 1 ? ia : (int)lenA - 1;
    int ib = (int)(s - slotsA); ib = ib < (int)lenB - 1 ? ib : (int)lenB - 1;
    ia = ia > 0 ? ia : 0;
    ib = ib > 0 ? ib : 0;
    unsigned pidx = pA ? (baseA + (unsigned)ia) : (baseB + (unsigned)ib);
    unsigned pk_pre = spack[pidx];

    unsigned rem = total - cb;
    unsigned cmax = rem < 64u ? rem : 64u;       // multiple of 4
    unsigned aRem = slotsA > cb ? slotsA - cb : 0u;
    int nitA = (int)((aRem < cmax ? aRem : cmax) >> 2);
    int nitT = (int)(cmax >> 2);

    #pragma unroll 1
    for (int ph = 0; ph < 2; ++ph){
      int it0 = ph ? nitA : 0;
      int it1 = ph ? nitT : nitA;
      float4 h = ph ? hB : hA;
      unsigned len = ph ? lenB : lenA;
      unsigned sBase = ph ? slotsA : 0u;
      for (int it = it0; it < it1; ++it){
        int sl = (it << 2) + g;
        unsigned pk = (unsigned)__builtin_amdgcn_ds_bpermute(sl << 2, (int)pk_pre);
        unsigned eidx = cb + (unsigned)sl - sBase;
        uint2 u = *(const uint2*)(egoin + (size_t)(pk & 0x1FFFFu)*D + q4);
        float4 rv = *(const float4*)&srel[(pk >> 17)*RELP + q4];
        float4 t = bfq(u);
        float p = (h.x*t.x)*rv.x;
        p = fmaf(h.y*t.y, rv.y, p);
        p = fmaf(h.z*t.z, rv.z, p);
        p = fmaf(h.w*t.w, rv.w, p);
        #pragma unroll
        for (int m = 1; m <= 8; m <<= 1) p += __shfl_xor(p, m, 64);
        float l = fmaxf(p, 0.01f*p);
        float ex = (eidx < len) ? __expf(l) : 0.f;
        dn += ex;
        ac.x = fmaf(ex, t.x, ac.x); ac.y = fmaf(ex, t.y, ac.y);
        ac.z = fmaf(ex, t.z, ac.z); ac.w = fmaf(ex, t.w, ac.w);
      }
      if (ph == 0 && !flA && slotsA <= cb + cmax){ flush(aA); flA = true; }
    }
  }
  if (!flA) flush(aA);   // total==0 / lenA==0 case
  flush(aB);

  if (g == 0){
    *(float4*)&sx1[slotA][q4] = make_float4(hA.x+aA.x, hA.y+aA.y, hA.z+aA.z, hA.w+aA.w);
    *(float4*)&sx2[slotA][q4] = make_float4(hA.x*aA.x, hA.y*aA.y, hA.z*aA.z, hA.w*aA.w);
    *(float4*)&sx1[slotB][q4] = make_float4(hB.x+aB.x, hB.y+aB.y, hB.z+aB.z, hB.w+aB.w);
    *(float4*)&sx2[slotB][q4] = make_float4(hB.x*aB.x, hB.y*aB.y, hB.z*aB.z, hB.w*aB.w);
  }

  float nvA = 0.f, nvB = 0.f;
  #pragma unroll
  for (int c = 0; c < 16; ++c){
    float4 w1 = bfq(*(const uint2*)&sW1b[c*128 + lane*2]);
    float4 w2 = bfq(*(const uint2*)&sW2b[c*128 + lane*2]);
    float4 xa1 = *(const float4*)&sx1[slotA][c*4];
    float4 xa2 = *(const float4*)&sx2[slotA][c*4];
    float4 xb1 = *(const float4*)&sx1[slotB][c*4];
    float4 xb2 = *(const float4*)&sx2[slotB][c*4];
    nvA = fmaf(xa1.x, w1.x, nvA); nvA = fmaf(xa1.y, w1.y, nvA);
    nvA = fmaf(xa1.z, w1.z, nvA); nvA = fmaf(xa1.w, w1.w, nvA);
    nvA = fmaf(xa2.x, w2.x, nvA); nvA = fmaf(xa2.y, w2.y, nvA);
    nvA = fmaf(xa2.z, w2.z, nvA); nvA = fmaf(xa2.w, w2.w, nvA);
    nvB = fmaf(xb1.x, w1.x, nvB); nvB = fmaf(xb1.y, w1.y, nvB);
    nvB = fmaf(xb1.z, w1.z, nvB); nvB = fmaf(xb1.w, w1.w, nvB);
    nvB = fmaf(xb2.x, w2.x, nvB); nvB = fmaf(xb2.y, w2.y, nvB);
    nvB = fmaf(xb2.z, w2.z, nvB); nvB = fmaf(xb2.w, w2.w, nvB);
  }
  nvA = fmaxf(nvA, 0.01f*nvA);
  nvB = fmaxf(nvB, 0.01f*nvB);
  float s2A = nvA*nvA, s2B = nvB*nvB;
  #pragma unroll
  for (int m = 1; m <= 32; m <<= 1){
    s2A += __shfl_xor(s2A, m, 64);
    s2B += __shfl_xor(s2B, m, 64);
  }
  nvA = nvA / fmaxf(sqrtf(s2A), EPS_NORM);
  nvB = nvB / fmaxf(sqrtf(s2B), EPS_NORM);

  if (FINAL){
    float z0A = bf2f(ego0[(size_t)nA*D + lane]);
    float z1A = bf2f(egoin[(size_t)nA*D + lane]);
    float z0B = bf2f(ego0[(size_t)nB*D + lane]);
    float z1B = bf2f(egoin[(size_t)nB*D + lane]);
    out[(size_t)out_row(nA)*D + lane] = (z0A + z1A + nvA) * (1.f/3.f);
    out[(size_t)out_row(nB)*D + lane] = (z0B + z1B + nvB) * (1.f/3.f);
  } else {
    egoout[(size_t)nA*D + lane] = f2bf(nvA);
    egoout[(size_t)nB*D + lane] = f2bf(nvB);
  }
}

extern "C" void kernel_launch(void* const* d_in, const int* in_sizes, int n_in,
                              void* d_out, int out_size, void* d_ws, size_t ws_size,
                              hipStream_t stream) {
  const float* user = (const float*)d_in[0];
  const float* ent  = (const float*)d_in[1];
  const float* relE = (const float*)d_in[2];
  const float* W1   = (const float*)d_in[3];
  const float* W2   = (const float*)d_in[4];
  const int*   src  = (const int*)d_in[5];
  const int*   dst  = (const int*)d_in[6];
  const int*   rel  = (const int*)d_in[7];
  float* out = (float*)d_out;

  char* ws = (char*)d_ws;
  unsigned short* ego0 = (unsigned short*)ws; ws += (size_t)N_NODES*D*sizeof(unsigned short);
  unsigned short* ego1 = (unsigned short*)ws; ws += (size_t)N_NODES*D*sizeof(unsigned short);
  unsigned* spack = (unsigned*)ws;            ws += (size_t)N_NODES*ELLW*sizeof(unsigned);
  unsigned* cnt = (unsigned*)ws;              ws += (size_t)N_NODES*sizeof(unsigned);
  unsigned* wpack = (unsigned*)ws;            ws += (size_t)D*D*sizeof(unsigned);

  k_zero<<<(N_NODES+255)/256, 256, 0, stream>>>(cnt);
  k_init_scatter<<<2048, 256, 0, stream>>>(user, ent, W1, W2, src, dst, rel,
                                           ego0, wpack, cnt, spack);

  const int lb = N_NODES / NPB;   // 6250
  k_layer<false><<<lb, 512, 0, stream>>>(cnt, spack, wpack, relE, ego0, ego1, ego0, out);
  k_layer<true ><<<lb, 512, 0, stream>>>(cnt, spack, wpack, relE, ego1, ego1, ego0, out);
}

// Round 10
// 284.453 us; speedup vs baseline: 2.1196x; 1.2499x over previous
//
#include <hip/hip_runtime.h>
#include <hip/hip_bf16.h>
#include <math.h>

#define N_USERS 20000
#define N_ENT   80000
#define N_NODES 100000
#define D 64
#define N_REL 33
#define E_EDGES 1250000
#define ELLW 40
#define EPS_ATT 1e-9f
#define EPS_NORM 1e-12f
#define RELP 68
#define NPB 32                       // nodes per block: 8 waves x 4 nodes
#define SXP 136                      // padded sX row (bf16), 272B = 17x16B
#define N_XCD 8
#define NODES_PER_XCD (N_NODES / N_XCD)   // 12500

typedef __attribute__((ext_vector_type(8))) short bf16x8;
typedef __attribute__((ext_vector_type(4))) float f32x4;

__device__ __forceinline__ int out_row(int n){
  return (n >= N_USERS) ? (n - N_USERS) : (n + N_ENT);
}
__device__ __forceinline__ unsigned short f2bf(float f){
  unsigned u = __float_as_uint(f);
  return (unsigned short)((u + 0x7FFFu + ((u >> 16) & 1u)) >> 16);  // RNE
}
__device__ __forceinline__ float bf2f(unsigned short b){
  return __uint_as_float(((unsigned)b) << 16);
}
__device__ __forceinline__ float4 bfq(uint2 u){  // 4 packed bf16 -> float4
  float4 r;
  r.x = __uint_as_float(u.x << 16);
  r.y = __uint_as_float(u.x & 0xFFFF0000u);
  r.z = __uint_as_float(u.y << 16);
  r.w = __uint_as_float(u.y & 0xFFFF0000u);
  return r;
}

__global__ void k_zero(unsigned* __restrict__ cnt){
  int i = blockIdx.x*blockDim.x + threadIdx.x;
  if (i < N_NODES) cnt[i] = 0u;
}

// ego0 bf16 conversion + W B-fragment pack + XCD-partitioned ELL scatter.
// wfrag[((s*4+t)*64 + l)*8 + i] = bf16(Wc[32s + 8*(l>>4) + i][16t + (l&15)])
// where Wc = [W1;W2] (128x64).  spack[n*ELLW + p] = rel<<17 | dst
__global__ void k_init_scatter(const float* __restrict__ user, const float* __restrict__ ent,
                               const float* __restrict__ W1, const float* __restrict__ W2,
                               const int* __restrict__ src, const int* __restrict__ dst,
                               const int* __restrict__ rel,
                               unsigned short* __restrict__ ego, unsigned short* __restrict__ wfrag,
                               unsigned* __restrict__ cnt, unsigned* __restrict__ spack){
  int stride = gridDim.x*blockDim.x;
  int tid0 = blockIdx.x*blockDim.x + threadIdx.x;
  // W pack in MFMA B-fragment order (8192 bf16)
  for (int i = tid0; i < 8192; i += stride){
    int ii = i & 7, l = (i >> 3) & 63, st = i >> 9;   // st = s*4+t, 0..15
    int s = st >> 2, t = st & 3;
    int k = 32*s + 8*(l >> 4) + ii;
    int nn = 16*t + (l & 15);
    float wv = (k < 64) ? W1[k*64 + nn] : W2[(k-64)*64 + nn];
    wfrag[i] = f2bf(wv);
  }
  // ego conversion
  const int total4 = N_NODES * D / 4;
  for (int i = tid0; i < total4; i += stride){
    int idx = i*4, n = idx >> 6, d = idx & 63;
    float4 v = (n < N_USERS) ? *(const float4*)(user + (size_t)n*D + d)
                             : *(const float4*)(ent + (size_t)(n-N_USERS)*D + d);
    uint2 p;
    p.x = (unsigned)f2bf(v.x) | ((unsigned)f2bf(v.y) << 16);
    p.y = (unsigned)f2bf(v.z) | ((unsigned)f2bf(v.w) << 16);
    *(uint2*)(ego + idx) = p;
  }
  // XCD-partitioned ELL scatter: 8 block-sets each scan all edges, keep 1/8
  int xcd = blockIdx.x & (N_XCD-1);
  int rank = blockIdx.x >> 3;
  int nlo = xcd * NODES_PER_XCD, nhi = nlo + NODES_PER_XCD;
  const int e4 = E_EDGES / 4;
  int et = rank*256 + threadIdx.x;
  int estride = (gridDim.x >> 3) * 256;
  for (int i = et; i < e4; i += estride){
    int4 s = ((const int4*)src)[i];
    int4 d = ((const int4*)dst)[i];
    int4 r = ((const int4*)rel)[i];
    unsigned p;
    if (s.x >= nlo && s.x < nhi){
      p = atomicAdd(&cnt[s.x], 1u);
      if (p < ELLW) spack[(size_t)s.x*ELLW + p] = ((unsigned)r.x << 17) | (unsigned)d.x;
    }
    if (s.y >= nlo && s.y < nhi){
      p = atomicAdd(&cnt[s.y], 1u);
      if (p < ELLW) spack[(size_t)s.y*ELLW + p] = ((unsigned)r.y << 17) | (unsigned)d.y;
    }
    if (s.z >= nlo && s.z < nhi){
      p = atomicAdd(&cnt[s.z], 1u);
      if (p < ELLW) spack[(size_t)s.z*ELLW + p] = ((unsigned)r.z << 17) | (unsigned)d.z;
    }
    if (s.w >= nlo && s.w < nhi){
      p = atomicAdd(&cnt[s.w], 1u);
      if (p < ELLW) spack[(size_t)s.w*ELLW + p] = ((unsigned)r.w << 17) | (unsigned)d.w;
    }
  }
}

// 8 waves x 4 sequential nodes edge phase -> sX (bf16 A-fragments in LDS) ->
// MFMA node update: Y[32x64] = [X1 X2] * [W1;W2], one 16x16 C-tile per wave.
template<bool FINAL>
__global__ __launch_bounds__(512, 7) void k_layer(const unsigned* __restrict__ cnt,
    const unsigned* __restrict__ spack, const unsigned short* __restrict__ wfrag,
    const float* __restrict__ relE,
    const unsigned short* __restrict__ egoin, unsigned short* __restrict__ egoout,
    const unsigned short* __restrict__ ego0, float* __restrict__ out){
  __shared__ float srel[N_REL*RELP];                 // ~9 KB
  __shared__ unsigned short sX[NPB][SXP];            // 8.7 KB, X=[x1(0..63) x2(64..127)]
  __shared__ float part[2][16][4];                   // row-norm partials
  int tid = threadIdx.x;
  for (int i = tid; i < N_REL*D; i += 512){
    int r = i >> 6, k = i & 63;
    srel[r*RELP + k] = relE[i];
  }
  __syncthreads();

  int wave = tid >> 6, lane = tid & 63;
  int g = lane >> 4, q4 = (lane & 15) * 4;
  int n0 = blockIdx.x*NPB + wave*4;

  // ---- edge phase: 4 nodes sequentially ----
  for (int v = 0; v < 4; ++v){
    int n = n0 + v;
    unsigned len = cnt[n]; len = len < ELLW ? len : ELLW;
    int pli = (int)len - 1;
    int li = lane < pli ? lane : pli;
    li = li > 0 ? li : 0;
    unsigned pk_pre = spack[(size_t)n*ELLW + li];    // whole segment in one load
    float4 h = bfq(*(const uint2*)(egoin + (size_t)n*D + q4));
    float dn = 0.f;
    float4 ac = make_float4(0.f,0.f,0.f,0.f);
    int nit = (int)((len + 3u) >> 2);
    for (int it = 0; it < nit; ++it){
      int sl = (it << 2) + g;
      unsigned pk = (unsigned)__builtin_amdgcn_ds_bpermute(sl << 2, (int)pk_pre);
      uint2 u = *(const uint2*)(egoin + (size_t)(pk & 0x1FFFFu)*D + q4);
      float4 rv = *(const float4*)&srel[(pk >> 17)*RELP + q4];
      float4 t = bfq(u);
      float p = (h.x*t.x)*rv.x;
      p = fmaf(h.y*t.y, rv.y, p);
      p = fmaf(h.z*t.z, rv.z, p);
      p = fmaf(h.w*t.w, rv.w, p);
      #pragma unroll
      for (int m = 1; m <= 8; m <<= 1) p += __shfl_xor(p, m, 64);
      float l = fmaxf(p, 0.01f*p);
      float ex = (sl < (int)len) ? __expf(l) : 0.f;
      dn += ex;
      ac.x = fmaf(ex, t.x, ac.x); ac.y = fmaf(ex, t.y, ac.y);
      ac.z = fmaf(ex, t.z, ac.z); ac.w = fmaf(ex, t.w, ac.w);
    }
    #pragma unroll
    for (int m = 16; m <= 32; m <<= 1){
      dn   += __shfl_xor(dn,   m, 64);
      ac.x += __shfl_xor(ac.x, m, 64); ac.y += __shfl_xor(ac.y, m, 64);
      ac.z += __shfl_xor(ac.z, m, 64); ac.w += __shfl_xor(ac.w, m, 64);
    }
    float inv = 1.f / (dn + EPS_ATT);
    if (g == 0){
      float4 a = make_float4(ac.x*inv, ac.y*inv, ac.z*inv, ac.w*inv);
      int nloc = wave*4 + v;
      unsigned p0 = (unsigned)f2bf(h.x + a.x) | ((unsigned)f2bf(h.y + a.y) << 16);
      unsigned p1 = (unsigned)f2bf(h.z + a.z) | ((unsigned)f2bf(h.w + a.w) << 16);
      unsigned p2 = (unsigned)f2bf(h.x * a.x) | ((unsigned)f2bf(h.y * a.y) << 16);
      unsigned p3 = (unsigned)f2bf(h.z * a.z) | ((unsigned)f2bf(h.w * a.w) << 16);
      *(unsigned*)&sX[nloc][q4]          = p0;
      *(unsigned*)&sX[nloc][q4 + 2]      = p1;
      *(unsigned*)&sX[nloc][64 + q4]     = p2;
      *(unsigned*)&sX[nloc][64 + q4 + 2] = p3;
    }
  }
  __syncthreads();

  // ---- MFMA node update: wave -> C-tile (mt, nt) ----
  int mt = wave >> 2, nt = wave & 3;
  f32x4 acc = {0.f, 0.f, 0.f, 0.f};
  int arow = mt*16 + (lane & 15);
  int kg = (lane >> 4) * 8;
  #pragma unroll
  for (int s = 0; s < 4; ++s){
    bf16x8 af = *(const bf16x8*)&sX[arow][s*32 + kg];
    bf16x8 bfg = *(const bf16x8*)&wfrag[(size_t)(((s << 2) | nt)*64 + lane)*8];
    acc = __builtin_amdgcn_mfma_f32_16x16x32_bf16(af, bfg, acc, 0, 0, 0);
  }
  // lrelu + row-norm (rows span 4 waves' tiles -> LDS partial + barrier)
  float y[4], ss[4];
  #pragma unroll
  for (int r = 0; r < 4; ++r){
    float t = acc[r];
    t = fmaxf(t, 0.01f*t);
    y[r] = t; ss[r] = t*t;
  }
  #pragma unroll
  for (int m = 1; m <= 8; m <<= 1){
    #pragma unroll
    for (int r = 0; r < 4; ++r) ss[r] += __shfl_xor(ss[r], m, 64);
  }
  if ((lane & 15) == 0){
    int rbase = (lane >> 4) * 4;
    #pragma unroll
    for (int r = 0; r < 4; ++r) part[mt][rbase + r][nt] = ss[r];
  }
  __syncthreads();
  int col = nt*16 + (lane & 15);
  #pragma unroll
  for (int r = 0; r < 4; ++r){
    int rrow = (lane >> 4)*4 + r;
    float4 ps = *(const float4*)&part[mt][rrow][0];  // same addr per row: broadcast
    float nrm = sqrtf(ps.x + ps.y + ps.z + ps.w);
    float yv = y[r] / fmaxf(nrm, EPS_NORM);
    int n = blockIdx.x*NPB + mt*16 + rrow;
    if (FINAL){
      float z0 = bf2f(ego0[(size_t)n*D + col]);
      float z1 = bf2f(egoin[(size_t)n*D + col]);
      out[(size_t)out_row(n)*D + col] = (z0 + z1 + yv) * (1.f/3.f);
    } else {
      egoout[(size_t)n*D + col] = f2bf(yv);
    }
  }
}

extern "C" void kernel_launch(void* const* d_in, const int* in_sizes, int n_in,
                              void* d_out, int out_size, void* d_ws, size_t ws_size,
                              hipStream_t stream) {
  const float* user = (const float*)d_in[0];
  const float* ent  = (const float*)d_in[1];
  const float* relE = (const float*)d_in[2];
  const float* W1   = (const float*)d_in[3];
  const float* W2   = (const float*)d_in[4];
  const int*   src  = (const int*)d_in[5];
  const int*   dst  = (const int*)d_in[6];
  const int*   rel  = (const int*)d_in[7];
  float* out = (float*)d_out;

  char* ws = (char*)d_ws;
  unsigned short* ego0 = (unsigned short*)ws;  ws += (size_t)N_NODES*D*sizeof(unsigned short);
  unsigned short* ego1 = (unsigned short*)ws;  ws += (size_t)N_NODES*D*sizeof(unsigned short);
  unsigned* spack = (unsigned*)ws;             ws += (size_t)N_NODES*ELLW*sizeof(unsigned);
  unsigned* cnt = (unsigned*)ws;               ws += (size_t)N_NODES*sizeof(unsigned);
  unsigned short* wfrag = (unsigned short*)ws; ws += (size_t)8192*sizeof(unsigned short);

  k_zero<<<(N_NODES+255)/256, 256, 0, stream>>>(cnt);
  k_init_scatter<<<2048, 256, 0, stream>>>(user, ent, W1, W2, src, dst, rel,
                                           ego0, wfrag, cnt, spack);

  const int lb = N_NODES / NPB;   // 3125
  k_layer<false><<<lb, 512, 0, stream>>>(cnt, spack, wfrag, relE, ego0, ego1, ego0, out);
  k_layer<true ><<<lb, 512, 0, stream>>>(cnt, spack, wfrag, relE, ego1, ego1, ego0, out);
}